// Round 1
// baseline (470.654 us; speedup 1.0000x reference)
//
#include <hip/hip_runtime.h>
#include <hip/hip_bf16.h>
#include <stdint.h>

#define S_LEN   4096
#define DIN     1280
#define DOUT    1280
#define N_LORA  4
#define R_LORA  16
#define M_TOT   32768               // B*S = 8*4096
#define KC      (DIN + N_LORA*R_LORA)   // 1344

typedef __attribute__((ext_vector_type(4))) float floatx4;
typedef __attribute__((ext_vector_type(8))) short shortx8;

static __device__ __forceinline__ unsigned short bf16_rne(float f) {
    union { float f; unsigned u; } v; v.f = f;
    unsigned u = v.u;
    u += 0x7fffu + ((u >> 16) & 1u);   // round-to-nearest-even
    return (unsigned short)(u >> 16);
}

static __device__ __forceinline__ void async16(const unsigned short* g, unsigned short* l) {
    __builtin_amdgcn_global_load_lds(
        (const __attribute__((address_space(1))) unsigned int*)g,
        (__attribute__((address_space(3))) unsigned int*)l, 16, 0, 0);
}

static __device__ __forceinline__ uint4 cvt8(const float* src) {
    const float4* p = (const float4*)src;
    float4 a = p[0], b = p[1];
    uint4 o;
    o.x = (unsigned)bf16_rne(a.x) | ((unsigned)bf16_rne(a.y) << 16);
    o.y = (unsigned)bf16_rne(a.z) | ((unsigned)bf16_rne(a.w) << 16);
    o.z = (unsigned)bf16_rne(b.x) | ((unsigned)bf16_rne(b.y) << 16);
    o.w = (unsigned)bf16_rne(b.z) | ((unsigned)bf16_rne(b.w) << 16);
    return o;
}

// ---- Kernel 1: x (fp32, M x 1280) -> xg cols [0,1280) (bf16, row stride 1344)
__global__ __launch_bounds__(256) void k_convert_x(const float* __restrict__ x,
                                                   unsigned short* __restrict__ xg) {
    int i = blockIdx.x * 256 + threadIdx.x;   // 5,242,880 threads total
    int e = i * 8;                            // < 41,943,040
    int m = e / DIN;
    int k = e - m * DIN;                      // multiple of 8 (1280 % 8 == 0)
    uint4 o = cvt8(x + e);
    *(uint4*)(xg + m * KC + k) = o;           // (m*1344 + k)*2 is 16B aligned
}

// ---- Kernel 1b: Wcat[o, 0:1280] = W[o,:];  Wcat[o, 1280 + n*16 + r] = Bw[n,o,r]
__global__ __launch_bounds__(256) void k_build_wcat(const float* __restrict__ W,
                                                    const float* __restrict__ Bw,
                                                    unsigned short* __restrict__ Wcat) {
    int i = blockIdx.x * 256 + threadIdx.x;   // 215,040 threads
    int e = i * 8;                            // < 1280*1344
    int o = e / KC;
    int c = e - o * KC;                       // multiple of 8
    const float* src;
    if (c < DIN) {
        src = W + o * DIN + c;
    } else {
        int j = c - DIN;                      // 0..63, multiple of 8
        int n = j >> 4, r = j & 15;           // r in {0,8}; 8 floats contiguous in Bw
        src = Bw + (n * DOUT + o) * R_LORA + r;
    }
    *(uint4*)(Wcat + o * KC + c) = cvt8(src);
}

// ---- Kernel 1c: A (N,R,DIN) fp32 -> Ab (64 x 1280) bf16 (flat contiguous)
__global__ __launch_bounds__(256) void k_convert_a(const float* __restrict__ A,
                                                   unsigned short* __restrict__ Ab) {
    int i = blockIdx.x * 256 + threadIdx.x;   // 10,240 threads
    int e = i * 8;                            // < 81,920
    *(uint4*)(Ab + e) = cvt8(A + e);
}

// ---- Kernel 2: g = scale * (xb @ Aflat^T), written into xg cols [1280,1344)
// BM=64, BN=64 (all ranks), BK=32; 256 threads, wave w computes rows [w*16, w*16+16)
__global__ __launch_bounds__(256) void k_lora_g(const unsigned short* __restrict__ xg_in,
                                                const unsigned short* __restrict__ Ab,
                                                const float* __restrict__ scalings,
                                                const float* __restrict__ masks,
                                                unsigned short* __restrict__ xg_out) {
    __shared__ unsigned short Xs[64 * 32];
    __shared__ unsigned short As[64 * 32];
    int tid = threadIdx.x;
    int wave = tid >> 6, lane = tid & 63;
    int mi = lane & 15, kq = lane >> 4;
    int m0 = blockIdx.x * 64;

    int chunk = tid;                  // 0..255 -> 64x32 tile, 16B chunks
    int srow = chunk >> 2;
    int skc  = (chunk & 3) * 8;

    floatx4 acc[4] = {};

    for (int k0 = 0; k0 < DIN; k0 += 32) {
        async16(xg_in + (m0 + srow) * KC + k0 + skc, Xs + chunk * 8);
        async16(Ab + srow * DIN + k0 + skc,          As + chunk * 8);
        __syncthreads();   // drains vmcnt before barrier (compiler-inserted)
        shortx8 xf = *(const shortx8*)(Xs + (wave * 16 + mi) * 32 + kq * 8);
#pragma unroll
        for (int ct = 0; ct < 4; ++ct) {
            shortx8 af = *(const shortx8*)(As + (ct * 16 + mi) * 32 + kq * 8);
            acc[ct] = __builtin_amdgcn_mfma_f32_16x16x32_bf16(xf, af, acc[ct], 0, 0, 0);
        }
        __syncthreads();
    }

#pragma unroll
    for (int ct = 0; ct < 4; ++ct) {
        float sc = scalings[ct];
        int j = ct * 16 + mi;         // j>>4 == ct since mi<16
#pragma unroll
        for (int reg = 0; reg < 4; ++reg) {
            int m = m0 + wave * 16 + kq * 4 + reg;
            int s = m & (S_LEN - 1);
            float wgt = sc * masks[ct * S_LEN + s];
            xg_out[m * KC + DIN + j] = bf16_rne(acc[ct][reg] * wgt);
        }
    }
}

// ---- Kernel 3: out = xg @ Wcat^T + bias  (M=32768, N=1280, K=1344)
// m97 structure: BM=BN=128, BK=32, 256 threads (4 waves, 2x2), 16 MFMA/K-step
__global__ __launch_bounds__(256) void k_main_gemm(const unsigned short* __restrict__ xg,
                                                   const unsigned short* __restrict__ Wcat,
                                                   const float* __restrict__ bias,
                                                   float* __restrict__ out) {
    __shared__ unsigned short As[128 * 32];
    __shared__ unsigned short Bs[128 * 32];
    int tid = threadIdx.x;
    int wave = tid >> 6, lane = tid & 63;
    int bx = blockIdx.x;
    int cb = bx % 10, rb = bx / 10;       // 256 row-blocks x 10 col-blocks
    int m0 = rb * 128, n0 = cb * 128;
    int wr = wave >> 1, wc = wave & 1;
    int mi = lane & 15, kq = lane >> 4;

    // staging: 128x32 bf16 tile = 512 x 16B chunks; thread does chunks tid, tid+256
    int c0 = tid, c1 = tid + 256;
    int ar0 = c0 >> 2, ak0 = (c0 & 3) * 8;
    int ar1 = c1 >> 2, ak1 = (c1 & 3) * 8;

    floatx4 acc[4][4] = {};

    for (int k0 = 0; k0 < KC; k0 += 32) {   // 42 K-steps
        async16(xg   + (m0 + ar0) * KC + k0 + ak0, As + c0 * 8);
        async16(xg   + (m0 + ar1) * KC + k0 + ak1, As + c1 * 8);
        async16(Wcat + (n0 + ar0) * KC + k0 + ak0, Bs + c0 * 8);
        async16(Wcat + (n0 + ar1) * KC + k0 + ak1, Bs + c1 * 8);
        __syncthreads();
        shortx8 af[4], bf[4];
#pragma unroll
        for (int t = 0; t < 4; ++t) {
            af[t] = *(const shortx8*)(As + (wr * 64 + t * 16 + mi) * 32 + kq * 8);
            bf[t] = *(const shortx8*)(Bs + (wc * 64 + t * 16 + mi) * 32 + kq * 8);
        }
#pragma unroll
        for (int i = 0; i < 4; ++i)
#pragma unroll
            for (int j = 0; j < 4; ++j)
                acc[i][j] = __builtin_amdgcn_mfma_f32_16x16x32_bf16(af[i], bf[j], acc[i][j], 0, 0, 0);
        __syncthreads();
    }

    // epilogue: C/D layout col=lane&15, row=(lane>>4)*4+reg  [m89/m91-verified]
#pragma unroll
    for (int j = 0; j < 4; ++j) {
        int col = n0 + wc * 64 + j * 16 + mi;
        float bv = bias[col];
#pragma unroll
        for (int i = 0; i < 4; ++i) {
            int rbase = m0 + wr * 64 + i * 16 + kq * 4;
#pragma unroll
            for (int reg = 0; reg < 4; ++reg) {
                out[(rbase + reg) * DOUT + col] = acc[i][j][reg] + bv;
            }
        }
    }
}

extern "C" void kernel_launch(void* const* d_in, const int* in_sizes, int n_in,
                              void* d_out, int out_size, void* d_ws, size_t ws_size,
                              hipStream_t stream) {
    const float* x     = (const float*)d_in[0];  // (8,4096,1280)
    const float* W     = (const float*)d_in[1];  // (1280,1280)
    const float* bias  = (const float*)d_in[2];  // (1280,)
    const float* A     = (const float*)d_in[3];  // (4,16,1280)
    const float* Bw    = (const float*)d_in[4];  // (4,1280,16)
    const float* scal  = (const float*)d_in[5];  // (4,)
    const float* masks = (const float*)d_in[6];  // (4,4096)
    float* out = (float*)d_out;

    unsigned short* xg   = (unsigned short*)d_ws;              // 32768 x 1344 bf16
    unsigned short* Wcat = xg + (size_t)M_TOT * KC;            // 1280 x 1344 bf16
    unsigned short* Ab   = Wcat + (size_t)DOUT * KC;           // 64 x 1280 bf16
    // total ws usage: 91,684,864 bytes

    k_convert_x<<<(M_TOT * DIN) / (8 * 256), 256, 0, stream>>>(x, xg);
    k_build_wcat<<<(DOUT * KC) / (8 * 256), 256, 0, stream>>>(W, Bw, Wcat);
    k_convert_a<<<(N_LORA * R_LORA * DIN) / (8 * 256), 256, 0, stream>>>(A, Ab);
    k_lora_g<<<M_TOT / 64, 256, 0, stream>>>(xg, Ab, scal, masks, xg);
    k_main_gemm<<<(M_TOT / 128) * (DOUT / 128), 256, 0, stream>>>(xg, Wcat, bias, out);
}